// Round 3
// baseline (1063.433 us; speedup 1.0000x reference)
//
#include <hip/hip_runtime.h>
#include <math.h>

// AnomalyTransformer forward. bf16-MFMA GEMMs (fp32 accumulate).
// Round 6: barrier-free-K GEMM (B-panel resident in LDS, pre-swizzled
// weights, A direct from L2, 32x32x16 MFMA, 512 thr), setup merged to 2
// launches, lnf fused into final projection. Dispatches 32 -> 25.
// B=8, WIN=512, D=512, H=8, EH=64, L=3, FF=512.

typedef unsigned short ushort;
typedef __attribute__((ext_vector_type(8))) ushort ushort8;
typedef __attribute__((ext_vector_type(4))) ushort ushort4v;
typedef __attribute__((ext_vector_type(8))) short short8;
typedef __attribute__((ext_vector_type(4))) float float4v;
typedef __attribute__((ext_vector_type(16))) float float16v;

__device__ inline ushort f2bf(float f) {
  union { float f; unsigned u; } v; v.f = f;
  return (ushort)((v.u + 0x7fffu + ((v.u >> 16) & 1u)) >> 16);
}

__device__ inline void gload16(const void* g, void* l) {
  __builtin_amdgcn_global_load_lds(
      (const __attribute__((address_space(1))) unsigned int*)g,
      (__attribute__((address_space(3))) unsigned int*)l, 16, 0, 0);
}

// ---------------- embed: wrap-pad conv1d(k=3) + sinusoidal PE ----------------
__global__ __launch_bounds__(512) void embed_kernel(const float* __restrict__ x,
                                                    const float* __restrict__ ck,
                                                    float* __restrict__ h,
                                                    ushort* __restrict__ hb) {
  int bt = blockIdx.x;
  int b = bt >> 9, t = bt & 511;
  int co = threadIdx.x;
  __shared__ float xs[3][38];
  if (co < 114) {
    int w = co / 38, ci = co - w * 38;
    int r = (t - 1 + w + 512) & 511;
    xs[w][ci] = x[((long)(b << 9) + r) * 38 + ci];
  }
  __syncthreads();
  float acc = 0.f;
#pragma unroll
  for (int w = 0; w < 3; ++w)
#pragma unroll
    for (int ci = 0; ci < 38; ++ci)
      acc = fmaf(xs[w][ci], ck[(w * 38 + ci) * 512 + co], acc);
  float div = expf((float)(co & ~1) * (-9.210340371976184f / 512.f));
  float ang = (float)t * div;
  float pe = (co & 1) ? cosf(ang) : sinf(ang);
  float o = acc + pe;
  h[(long)bt * 512 + co] = o;
  hb[(long)bt * 512 + co] = f2bf(o);
}

// ------ merged weight convert+transpose+swizzle: fp32 [k][n] -> bf16 [n][k^] --
// Stores chunk c (8 ushorts) of row n at chunk (c ^ (n&7)) -> bank-uniform
// ds_read_b128 in gemm_wp after linear global_load_lds staging.
__global__ __launch_bounds__(256) void prep_kernel(
    const float* __restrict__ Wq, const float* __restrict__ Wk,
    const float* __restrict__ Wv, const float* __restrict__ Wo,
    const float* __restrict__ W1, const float* __restrict__ W2,
    ushort* __restrict__ wqkv, ushort* __restrict__ wo3,
    ushort* __restrict__ w13, ushort* __restrict__ w23) {
  int z = blockIdx.z;
  int ten = z / 3, l = z - ten * 3;
  const float* w;
  ushort* o;
  switch (ten) {
    case 0: w = Wq; o = wqkv + (long)l * 786432; break;
    case 1: w = Wk; o = wqkv + (long)l * 786432 + 262144; break;
    case 2: w = Wv; o = wqkv + (long)l * 786432 + 524288; break;
    case 3: w = Wo; o = wo3 + (long)l * 262144; break;
    case 4: w = W1; o = w13 + (long)l * 262144; break;
    default: w = W2; o = w23 + (long)l * 262144; break;
  }
  w += (long)l * 262144;
  int n = blockIdx.x * 256 + threadIdx.x;
  int c = blockIdx.y;  // k-chunk 0..63 (k0 = c*8)
  ushort8 v;
#pragma unroll
  for (int i = 0; i < 8; ++i) v[i] = f2bf(w[(long)(c * 8 + i) * 512 + n]);
  *(ushort8*)&o[(long)n * 512 + ((c ^ (n & 7)) << 3)] = v;
}

// -------- merged bias-concat + Ws transpose ----------
__global__ __launch_bounds__(512) void bw_kernel(const float* __restrict__ bq,
                                                 const float* __restrict__ bk,
                                                 const float* __restrict__ bv,
                                                 const float* __restrict__ Ws,
                                                 float* __restrict__ bqkv,
                                                 float* __restrict__ WsT) {
  int z = blockIdx.x, t = threadIdx.x;
  if (z < 3) {
    bqkv[z * 1536 + t] = bq[z * 512 + t];
    bqkv[z * 1536 + 512 + t] = bk[z * 512 + t];
    bqkv[z * 1536 + 1024 + t] = bv[z * 512 + t];
  } else {
    int l = z - 3;
#pragma unroll
    for (int hh = 0; hh < 8; ++hh)
      WsT[(long)l * 4096 + hh * 512 + t] = Ws[(long)l * 4096 + t * 8 + hh];
  }
}

// ------- weight-panel-resident GEMM: C = A@B^T + bias (+gelu) ------------
// K=512 fixed. BM=128, BN=64, 512 threads (8 waves, 4x2), 32x32x16 MFMA.
// B panel (64 KB, pre-swizzled) staged once; A frags direct from L2.
// Zero barriers in K-loop. VST: co-store transposed V for QKV cols>=1024.
template <bool GELU_, bool CBF16, bool VST>
__global__ __launch_bounds__(512, 4) void gemm_wp(
    const ushort* __restrict__ A,
    const ushort* __restrict__ B,
    const float* __restrict__ bias,
    void* __restrict__ Cv, int ldc,
    ushort* __restrict__ vTout) {
  __shared__ ushort Bs[32768];  // 64 KB
  int t = threadIdx.x;
  int m0 = blockIdx.y * 128, n0 = blockIdx.x * 64;
  int w = t >> 6, lane = t & 63;
  int l31 = lane & 31, q1 = lane >> 5;
  int wrow = (w >> 1) * 32, wcol = (w & 1) * 32;

  // stage B panel: 64 rows x 1 KB contiguous (pre-swizzled) -> linear LDS
  {
    const ushort* gb = B + (long)n0 * 512;
#pragma unroll
    for (int it = 0; it < 8; ++it)
      gload16(gb + it * 4096 + t * 8, &Bs[it * 4096 + t * 8]);
  }
  __syncthreads();  // drains vmcnt: panel ready

  float16v acc0, acc1;
#pragma unroll
  for (int i = 0; i < 16; ++i) { acc0[i] = 0.f; acc1[i] = 0.f; }

  const ushort* ga = &A[(long)(m0 + wrow + l31) * 512 + q1 * 8];
  int brow = wcol + l31;
  int bx = brow & 7;
  const ushort* bp_ = &Bs[brow * 512];

#pragma unroll
  for (int k0 = 0; k0 < 512; k0 += 32) {
    short8 a0 = *(const short8*)&ga[k0];
    short8 a1 = *(const short8*)&ga[k0 + 16];
    int kc = (k0 >> 3) + q1;
    short8 b0 = *(const short8*)&bp_[(kc ^ bx) << 3];
    short8 b1 = *(const short8*)&bp_[((kc + 2) ^ bx) << 3];
    acc0 = __builtin_amdgcn_mfma_f32_32x32x16_bf16(a0, b0, acc0, 0, 0, 0);
    acc1 = __builtin_amdgcn_mfma_f32_32x32x16_bf16(a1, b1, acc1, 0, 0, 0);
  }

  // epilogue: C row = (reg&3) + 8*(reg>>2) + 4*q1 (+wrow), col = wcol + l31
  int col = n0 + wcol + l31;
  float bvv = bias ? bias[col] : 0.f;
#pragma unroll
  for (int rg = 0; rg < 4; ++rg) {
    int rbase = m0 + wrow + rg * 8 + q1 * 4;
    float vv[4];
#pragma unroll
    for (int rr = 0; rr < 4; ++rr) {
      float v = acc0[rg * 4 + rr] + acc1[rg * 4 + rr] + bvv;
      if (GELU_) v = 0.5f * v * (1.f + erff(v * 0.7071067811865476f));
      vv[rr] = v;
      if (CBF16)
        ((ushort*)Cv)[(long)(rbase + rr) * ldc + col] = f2bf(v);
      else
        ((float*)Cv)[(long)(rbase + rr) * ldc + col] = v;
    }
    if (VST && n0 >= 1024) {  // V region: also store transposed [bh][d][s]
      int d = wcol + l31;     // (col-1024)&63 for 64-aligned n0 in V region
      int hh = (n0 - 1024) >> 6;
      int bb2 = rbase >> 9, s0 = rbase & 511;
      ushort4v pk;
#pragma unroll
      for (int rr = 0; rr < 4; ++rr) pk[rr] = f2bf(vv[rr]);
      *(ushort4v*)&vTout[((long)(bb2 * 8 + hh) * 64 + d) * 512 + s0] = pk;
    }
  }
}

// ---------------- fused attention ----------------
// grid (16 mtiles, 64 bh), 256 threads (4 waves). 32 rows per block.
// Q/K frags direct from qkv (L2), V frags direct from vT (L2); Ps in LDS.
// Also computes sigma logits (h @ Ws col) for its rows -> prior/sigma.
__global__ __launch_bounds__(256, 2) void attn_fused(
    const ushort* __restrict__ qkv, const ushort* __restrict__ vT,
    const float* __restrict__ h, const float* __restrict__ WsT,
    const float* __restrict__ bsw,
    float* __restrict__ series, float* __restrict__ prior,
    float* __restrict__ sigma, ushort* __restrict__ t1b) {
  __shared__ ushort Ps[32 * 520];  // softmax'd P, bf16 (33.3 KB)
  __shared__ float red[128];
  __shared__ float sgc[96];

  int t = threadIdx.x;
  int m0 = blockIdx.x * 32;
  int bh = blockIdx.y;
  int b = bh >> 3, hh = bh & 7;
  int w = t >> 6, lane = t & 63;
  int fm = lane & 15, q4 = lane >> 4;
  int wc = w * 128;
  long rowg = (long)b * 512;

  // ---- fused sigma logits: 8 threads per row, 64 k each ----
  {
    int r = t >> 3, p = t & 7;
    const float* hrow = &h[(rowg + m0 + r) * 512 + p * 64];
    const float* wcol = &WsT[hh * 512 + p * 64];
    float s = 0.f;
#pragma unroll
    for (int i = 0; i < 16; ++i) {
      float4 hv = *(const float4*)&hrow[i * 4];
      float4 wv = *(const float4*)&wcol[i * 4];
      s += hv.x * wv.x + hv.y * wv.y + hv.z * wv.z + hv.w * wv.w;
    }
    s += __shfl_xor(s, 1); s += __shfl_xor(s, 2); s += __shfl_xor(s, 4);
    if (p == 0) {
      float xv = s + bsw[hh];
      float sig = 1.f / (1.f + __expf(-5.f * xv)) + 1e-5f;
      float sgv = expm1f(sig * 1.0986122886681098f);
      sgc[r * 3] = sgv;
      sgc[r * 3 + 1] = 0.3989422804014327f / sgv;
      sgc[r * 3 + 2] = 1.f / sgv;
    }
  }

  // ---- S = Q @ K^T, fragments straight from global (L2-resident) ----
  float4v acc[2][8];
#pragma unroll
  for (int i = 0; i < 2; ++i)
#pragma unroll
    for (int j = 0; j < 8; ++j) acc[i][j] = (float4v){0.f, 0.f, 0.f, 0.f};

  const ushort* qbase = &qkv[(rowg + m0) * 1536 + hh * 64];
  const ushort* kbase = &qkv[rowg * 1536 + 512 + hh * 64];
#pragma unroll
  for (int ks = 0; ks < 2; ++ks) {
    int ko = ks * 32 + q4 * 8;
    short8 a[2], bfr[8];
#pragma unroll
    for (int i = 0; i < 2; ++i)
      a[i] = *(const short8*)&qbase[(long)(16 * i + fm) * 1536 + ko];
#pragma unroll
    for (int j = 0; j < 8; ++j)
      bfr[j] = *(const short8*)&kbase[(long)(wc + 16 * j + fm) * 1536 + ko];
#pragma unroll
    for (int i = 0; i < 2; ++i)
#pragma unroll
      for (int j = 0; j < 8; ++j)
        acc[i][j] = __builtin_amdgcn_mfma_f32_16x16x32_bf16(a[i], bfr[j], acc[i][j], 0, 0, 0);
  }

  // ---- softmax over full rows (512 cols per row) ----
#pragma unroll
  for (int i = 0; i < 2; ++i)
#pragma unroll
    for (int j = 0; j < 8; ++j)
#pragma unroll
      for (int r = 0; r < 4; ++r) acc[i][j][r] *= 0.125f;

  float mrow[2][4];
#pragma unroll
  for (int i = 0; i < 2; ++i)
#pragma unroll
    for (int r = 0; r < 4; ++r) {
      float m = acc[i][0][r];
#pragma unroll
      for (int j = 1; j < 8; ++j) m = fmaxf(m, acc[i][j][r]);
#pragma unroll
      for (int off = 1; off < 16; off <<= 1) m = fmaxf(m, __shfl_xor(m, off));
      mrow[i][r] = m;
    }
  if (fm == 0) {
#pragma unroll
    for (int i = 0; i < 2; ++i)
#pragma unroll
      for (int r = 0; r < 4; ++r)
        red[(16 * i + q4 * 4 + r) * 4 + w] = mrow[i][r];
  }
  __syncthreads();
#pragma unroll
  for (int i = 0; i < 2; ++i)
#pragma unroll
    for (int r = 0; r < 4; ++r) {
      const float* rp = &red[(16 * i + q4 * 4 + r) * 4];
      mrow[i][r] = fmaxf(fmaxf(rp[0], rp[1]), fmaxf(rp[2], rp[3]));
    }
  float lrow[2][4];
#pragma unroll
  for (int i = 0; i < 2; ++i)
#pragma unroll
    for (int r = 0; r < 4; ++r) {
      float s = 0.f;
#pragma unroll
      for (int j = 0; j < 8; ++j) {
        float e = __expf(acc[i][j][r] - mrow[i][r]);
        acc[i][j][r] = e;
        s += e;
      }
#pragma unroll
      for (int off = 1; off < 16; off <<= 1) s += __shfl_xor(s, off);
      lrow[i][r] = s;
    }
  __syncthreads();  // all waves done reading red(max)
  if (fm == 0) {
#pragma unroll
    for (int i = 0; i < 2; ++i)
#pragma unroll
      for (int r = 0; r < 4; ++r)
        red[(16 * i + q4 * 4 + r) * 4 + w] = lrow[i][r];
  }
  __syncthreads();
#pragma unroll
  for (int i = 0; i < 2; ++i)
#pragma unroll
    for (int r = 0; r < 4; ++r) {
      const float* rp = &red[(16 * i + q4 * 4 + r) * 4];
      lrow[i][r] = 1.f / (rp[0] + rp[1] + rp[2] + rp[3]);
    }

  // ---- write series (fp32 global) + Ps (bf16 LDS) ----
  float* serp = series + ((long)bh << 18);
#pragma unroll
  for (int i = 0; i < 2; ++i)
#pragma unroll
    for (int r = 0; r < 4; ++r) {
      int row = 16 * i + q4 * 4 + r;
      float inv = lrow[i][r];
#pragma unroll
      for (int j = 0; j < 8; ++j) {
        int col = wc + 16 * j + fm;
        float v = acc[i][j][r] * inv;
        serp[(long)(m0 + row) * 512 + col] = v;
        Ps[row * 520 + col] = f2bf(v);
      }
    }
  __syncthreads();  // Ps (and sgc) visible to all waves

  // ---- O = P @ V : V frags direct from vT (L2), zero barriers ----
  float4v acc2[2] = {{0.f, 0.f, 0.f, 0.f}, {0.f, 0.f, 0.f, 0.f}};
  int wn = w * 16;
  const ushort* vbase = &vT[((long)bh * 64 + wn + fm) * 512];
#pragma unroll
  for (int c = 0; c < 8; ++c) {
#pragma unroll
    for (int ks = 0; ks < 2; ++ks) {
      int ko = ks * 32 + q4 * 8;
      short8 b2 = *(const short8*)&vbase[c * 64 + ko];
#pragma unroll
      for (int i = 0; i < 2; ++i) {
        short8 a2 = *(const short8*)&Ps[(16 * i + fm) * 520 + c * 64 + ko];
        acc2[i] = __builtin_amdgcn_mfma_f32_16x16x32_bf16(a2, b2, acc2[i], 0, 0, 0);
      }
    }
  }
#pragma unroll
  for (int i = 0; i < 2; ++i)
#pragma unroll
    for (int r = 0; r < 4; ++r)
      t1b[(rowg + m0 + 16 * i + q4 * 4 + r) * 512 + hh * 64 + wn + fm] =
          f2bf(acc2[i][r]);

  // ---- prior + sigma for rows m0..m0+31 ----
  float* prip = prior + ((long)bh << 18);
  float* sigp = sigma + ((long)bh << 18);
  for (int it = t; it < 4096; it += 256) {
    int row = it >> 7;
    int c4 = (it & 127) << 2;
    float sgv = sgc[row * 3], inv = sgc[row * 3 + 1], rinv = sgc[row * 3 + 2];
    float ig = (float)(m0 + row);
    float4 pv, sv;
#pragma unroll
    for (int e = 0; e < 4; ++e) {
      float dd = ig - (float)(c4 + e);
      float rr = dd * rinv;
      ((float*)&pv)[e] = inv * __expf(-0.5f * rr * rr);
      ((float*)&sv)[e] = sgv;
    }
    *(float4*)&prip[(long)(m0 + row) * 512 + c4] = pv;
    *(float4*)&sigp[(long)(m0 + row) * 512 + c4] = sv;
  }
}

// ---------------- residual + layernorm (fp32 out + optional bf16 out) -------
__global__ __launch_bounds__(256) void ln_kernel(const float* __restrict__ x,
                                                 const float* __restrict__ delta,
                                                 const float* __restrict__ g,
                                                 const float* __restrict__ bb,
                                                 float* __restrict__ out,
                                                 ushort* __restrict__ hb) {
  long row = blockIdx.x;
  int tid = threadIdx.x;
  int c = tid * 2;
  float2 xv = *(const float2*)&x[row * 512 + c];
  if (delta) {
    float2 dv = *(const float2*)&delta[row * 512 + c];
    xv.x += dv.x; xv.y += dv.y;
  }
  float s = xv.x + xv.y;
  float q = xv.x * xv.x + xv.y * xv.y;
#pragma unroll
  for (int off = 1; off < 64; off <<= 1) {
    s += __shfl_xor(s, off);
    q += __shfl_xor(q, off);
  }
  __shared__ float red[8];
  int wid = tid >> 6;
  if ((tid & 63) == 0) { red[wid] = s; red[wid + 4] = q; }
  __syncthreads();
  float S = red[0] + red[1] + red[2] + red[3];
  float Q = red[4] + red[5] + red[6] + red[7];
  float mean = S * (1.f / 512.f);
  float var = Q * (1.f / 512.f) - mean * mean;
  float rstd = rsqrtf(var + 1e-3f);
  float2 o;
  o.x = (xv.x - mean) * rstd * g[c] + bb[c];
  o.y = (xv.y - mean) * rstd * g[c + 1] + bb[c + 1];
  *(float2*)&out[row * 512 + c] = o;
  if (hb) {
    unsigned pk = ((unsigned)f2bf(o.y) << 16) | (unsigned)f2bf(o.x);
    ((unsigned*)hb)[row * 256 + tid] = pk;
  }
}

// ---------------- final LN + projection (wave per row) ----------------
__global__ __launch_bounds__(256) void proj_ln(const float* __restrict__ A,
                                               const float* __restrict__ g,
                                               const float* __restrict__ bb,
                                               const float* __restrict__ W,
                                               const float* __restrict__ bp,
                                               float* __restrict__ C) {
  long row = (long)blockIdx.x * 4 + (threadIdx.x >> 6);
  int lane = threadIdx.x & 63;
  int k0 = lane * 8;
  float xv[8];
  {
    float4 x0 = *(const float4*)&A[row * 512 + k0];
    float4 x1 = *(const float4*)&A[row * 512 + k0 + 4];
    xv[0] = x0.x; xv[1] = x0.y; xv[2] = x0.z; xv[3] = x0.w;
    xv[4] = x1.x; xv[5] = x1.y; xv[6] = x1.z; xv[7] = x1.w;
  }
  float s = 0.f, q = 0.f;
#pragma unroll
  for (int e = 0; e < 8; ++e) { s += xv[e]; q += xv[e] * xv[e]; }
#pragma unroll
  for (int off = 1; off < 64; off <<= 1) {
    s += __shfl_xor(s, off);
    q += __shfl_xor(q, off);
  }
  float mean = s * (1.f / 512.f);
  float var = q * (1.f / 512.f) - mean * mean;
  float rstd = rsqrtf(var + 1e-3f);
  float acc[38];
#pragma unroll
  for (int j = 0; j < 38; ++j) acc[j] = 0.f;
#pragma unroll
  for (int e = 0; e < 8; ++e) {
    float xn = (xv[e] - mean) * rstd * g[k0 + e] + bb[k0 + e];
    const float* wr = &W[(long)(k0 + e) * 38];
#pragma unroll
    for (int j = 0; j < 38; ++j) acc[j] = fmaf(xn, wr[j], acc[j]);
  }
#pragma unroll
  for (int j = 0; j < 38; ++j)
#pragma unroll
    for (int off = 32; off; off >>= 1) acc[j] += __shfl_xor(acc[j], off);
  if (lane == 0) {
#pragma unroll
    for (int j = 0; j < 38; ++j) C[row * 38 + j] = acc[j] + bp[j];
  }
}

extern "C" void kernel_launch(void* const* d_in, const int* in_sizes, int n_in,
                              void* d_out, int out_size, void* d_ws, size_t ws_size,
                              hipStream_t stream) {
  (void)in_sizes; (void)n_in; (void)out_size; (void)ws_size;
  const float* x    = (const float*)d_in[0];
  const float* ck   = (const float*)d_in[1];
  const float* Wq   = (const float*)d_in[2];
  const float* bq   = (const float*)d_in[3];
  const float* Wk   = (const float*)d_in[4];
  const float* bk   = (const float*)d_in[5];
  const float* Wv   = (const float*)d_in[6];
  const float* bv   = (const float*)d_in[7];
  const float* Wsw  = (const float*)d_in[8];
  const float* bsw  = (const float*)d_in[9];
  const float* Wo   = (const float*)d_in[10];
  const float* bo   = (const float*)d_in[11];
  const float* W1   = (const float*)d_in[12];
  const float* b1   = (const float*)d_in[13];
  const float* W2   = (const float*)d_in[14];
  const float* b2   = (const float*)d_in[15];
  const float* ln1g = (const float*)d_in[16];
  const float* ln1b = (const float*)d_in[17];
  const float* ln2g = (const float*)d_in[18];
  const float* ln2b = (const float*)d_in[19];
  const float* lnfg = (const float*)d_in[20];
  const float* lnfb = (const float*)d_in[21];
  const float* Wp   = (const float*)d_in[22];
  const float* bp   = (const float*)d_in[23];
  float* out = (float*)d_out;

  // ws layout (same footprint)
  float* h    = (float*)d_ws;
  float* t1   = h + 2097152;
  float* t2   = t1 + 2097152;
  float* wst  = t2 + 2097152;           // 12288 used of 32768 slot
  float* bqkv = wst + 32768;            // 4608
  ushort* qkv  = (ushort*)(bqkv + 4608);        // 4096*1536
  ushort* wqkv = qkv + 6291456;                 // 3*1536*512
  ushort* wo3  = wqkv + 2359296;                // 3*512*512
  ushort* w13  = wo3 + 786432;
  ushort* w23  = w13 + 786432;
  // overlays: t1b = low half of t1 (bf16); hb = high half of t1;
  // vT = low half of t2 (dead before Wo writes t2).
  ushort* t1b = (ushort*)t1;                    // 2097152 ushorts
  ushort* hb  = (ushort*)(t1 + 1048576);        // 2097152 ushorts
  ushort* vT  = (ushort*)t2;                    // 2097152 ushorts

  float* series0 = out + 155648;
  float* prior0  = out + 50487296;
  float* sigma0  = out + 100818944;

  dim3 gPrep(2, 64, 18);
  prep_kernel<<<gPrep, 256, 0, stream>>>(Wq, Wk, Wv, Wo, W1, W2,
                                         wqkv, wo3, w13, w23);
  bw_kernel<<<6, 512, 0, stream>>>(bq, bk, bv, Wsw, bqkv, wst);

  embed_kernel<<<4096, 512, 0, stream>>>(x, ck, h, hb);

  dim3 gQKV(24, 32, 1);   // N=1536, M=4096 (BN=64, BM=128)
  dim3 gFull(8, 32, 1);   // N=512,  M=4096
  dim3 gAttn(16, 64, 1);  // 16 mtiles x 64 bh

  for (int l = 0; l < 3; ++l) {
    float* ser = series0 + (long)l * 16777216;
    float* pri = prior0  + (long)l * 16777216;
    float* sgm = sigma0  + (long)l * 16777216;

    // fused QKV projection -> qkv bf16 [4096][1536] + vT co-store
    gemm_wp<false, true, true><<<gQKV, 512, 0, stream>>>(
        hb, wqkv + (long)l * 786432, bqkv + l * 1536, qkv, 1536, vT);
    // fused attention: series/prior/sigma + sigma-logits + attn-out (t1b)
    attn_fused<<<gAttn, 256, 0, stream>>>(qkv, vT, h, wst + (long)l * 4096,
                                          bsw + (long)l * 8, ser, pri, sgm, t1b);
    // Wo projection (f32 out for residual)
    gemm_wp<false, false, false><<<gFull, 512, 0, stream>>>(
        t1b, wo3 + (long)l * 262144, bo + (long)l * 512, t2, 512, nullptr);
    ln_kernel<<<4096, 256, 0, stream>>>(h, t2, ln1g + l * 512, ln1b + l * 512, h, hb);
    // FF
    gemm_wp<true, true, false><<<gFull, 512, 0, stream>>>(
        hb, w13 + (long)l * 262144, b1 + (long)l * 512, t1b, 512, nullptr);
    gemm_wp<false, false, false><<<gFull, 512, 0, stream>>>(
        t1b, w23 + (long)l * 262144, b2 + (long)l * 512, t2, 512, nullptr);
    ln_kernel<<<4096, 256, 0, stream>>>(h, t2, ln2g + l * 512, ln2b + l * 512, h, hb);
  }

  proj_ln<<<1024, 256, 0, stream>>>(h, lnfg, lnfb, Wp, bp, out);
}

// Round 5
// 1012.180 us; speedup vs baseline: 1.0506x; 1.0506x over previous
//
#include <hip/hip_runtime.h>
#include <math.h>

// AnomalyTransformer forward. bf16-MFMA GEMMs (fp32 accumulate).
// Round 8: R7 with compile fix — nt stores use ext_vector float4v (HIP float4
// class type rejected by __builtin_nontemporal_store). GEMM = R2 gemm_bt;
// series/prior/sigma non-temporal to stop L2 thrash of qkv/vT/panels.
// B=8, WIN=512, D=512, H=8, EH=64, L=3, FF=512.

typedef unsigned short ushort;
typedef __attribute__((ext_vector_type(8))) ushort ushort8;
typedef __attribute__((ext_vector_type(4))) ushort ushort4v;
typedef __attribute__((ext_vector_type(8))) short short8;
typedef __attribute__((ext_vector_type(4))) float float4v;

__device__ inline ushort f2bf(float f) {
  union { float f; unsigned u; } v; v.f = f;
  return (ushort)((v.u + 0x7fffu + ((v.u >> 16) & 1u)) >> 16);
}

__device__ inline void gload16(const void* g, void* l) {
  __builtin_amdgcn_global_load_lds(
      (const __attribute__((address_space(1))) unsigned int*)g,
      (__attribute__((address_space(3))) unsigned int*)l, 16, 0, 0);
}

// ---------------- embed: wrap-pad conv1d(k=3) + sinusoidal PE ----------------
__global__ __launch_bounds__(512) void embed_kernel(const float* __restrict__ x,
                                                    const float* __restrict__ ck,
                                                    float* __restrict__ h,
                                                    ushort* __restrict__ hb) {
  int bt = blockIdx.x;
  int b = bt >> 9, t = bt & 511;
  int co = threadIdx.x;
  __shared__ float xs[3][38];
  if (co < 114) {
    int w = co / 38, ci = co - w * 38;
    int r = (t - 1 + w + 512) & 511;
    xs[w][ci] = x[((long)(b << 9) + r) * 38 + ci];
  }
  __syncthreads();
  float acc = 0.f;
#pragma unroll
  for (int w = 0; w < 3; ++w)
#pragma unroll
    for (int ci = 0; ci < 38; ++ci)
      acc = fmaf(xs[w][ci], ck[(w * 38 + ci) * 512 + co], acc);
  float div = expf((float)(co & ~1) * (-9.210340371976184f / 512.f));
  float ang = (float)t * div;
  float pe = (co & 1) ? cosf(ang) : sinf(ang);
  float o = acc + pe;
  h[(long)bt * 512 + co] = o;
  hb[(long)bt * 512 + co] = f2bf(o);
}

// ------ merged weight convert+transpose: fp32 [k][n] -> bf16 [n][k] ---------
__global__ __launch_bounds__(256) void prep_kernel(
    const float* __restrict__ Wq, const float* __restrict__ Wk,
    const float* __restrict__ Wv, const float* __restrict__ Wo,
    const float* __restrict__ W1, const float* __restrict__ W2,
    ushort* __restrict__ wqkv, ushort* __restrict__ wo3,
    ushort* __restrict__ w13, ushort* __restrict__ w23) {
  int z = blockIdx.z;
  int ten = z / 3, l = z - ten * 3;
  const float* w;
  ushort* o;
  switch (ten) {
    case 0: w = Wq; o = wqkv + (long)l * 786432; break;
    case 1: w = Wk; o = wqkv + (long)l * 786432 + 262144; break;
    case 2: w = Wv; o = wqkv + (long)l * 786432 + 524288; break;
    case 3: w = Wo; o = wo3 + (long)l * 262144; break;
    case 4: w = W1; o = w13 + (long)l * 262144; break;
    default: w = W2; o = w23 + (long)l * 262144; break;
  }
  w += (long)l * 262144;
  int n = blockIdx.x * 256 + threadIdx.x;
  int c = blockIdx.y;  // k-chunk 0..63 (k0 = c*8)
  ushort8 v;
#pragma unroll
  for (int i = 0; i < 8; ++i) v[i] = f2bf(w[(long)(c * 8 + i) * 512 + n]);
  *(ushort8*)&o[(long)n * 512 + c * 8] = v;
}

// -------- merged bias-concat + Ws transpose ----------
__global__ __launch_bounds__(512) void bw_kernel(const float* __restrict__ bq,
                                                 const float* __restrict__ bk,
                                                 const float* __restrict__ bv,
                                                 const float* __restrict__ Ws,
                                                 float* __restrict__ bqkv,
                                                 float* __restrict__ WsT) {
  int z = blockIdx.x, t = threadIdx.x;
  if (z < 3) {
    bqkv[z * 1536 + t] = bq[z * 512 + t];
    bqkv[z * 1536 + 512 + t] = bk[z * 512 + t];
    bqkv[z * 1536 + 1024 + t] = bv[z * 512 + t];
  } else {
    int l = z - 3;
#pragma unroll
    for (int hh = 0; hh < 8; ++hh)
      WsT[(long)l * 4096 + hh * 512 + t] = Ws[(long)l * 4096 + t * 8 + hh];
  }
}

// ------- bf16 GEMM: C = A@B^T + bias (+gelu). BM=128 BN=64 BK=32, dbuf ----
// A bf16 [M][K] (lda), B bf16 [N][K] (ldb). 4 waves, each 64x32 out subtile.
// VST: co-store transposed bf16 V (cols>=1024 of QKV output) into vTout.
template <bool GELU_, bool CBF16, bool VST>
__global__ __launch_bounds__(256) void gemm_bt(
    const ushort* __restrict__ A, int lda,
    const ushort* __restrict__ B, int ldb,
    const float* __restrict__ bias,
    void* __restrict__ Cv, int ldc, int K,
    ushort* __restrict__ vTout) {
  __shared__ ushort As[2][4096];  // [128][32] linear (64B row stride)
  __shared__ ushort Bs[2][2048];  // [64][32]
  int t = threadIdx.x;
  int m0 = blockIdx.y * 128, n0 = blockIdx.x * 64;
  int w = t >> 6, lane = t & 63;
  int wr = (w >> 1) * 64, wc = (w & 1) * 32;
  int fm = lane & 15, q4 = lane >> 4;
  float4v acc[4][2];
#pragma unroll
  for (int i = 0; i < 4; ++i)
#pragma unroll
    for (int j = 0; j < 2; ++j) acc[i][j] = (float4v){0.f, 0.f, 0.f, 0.f};

  int kk = (lane & 3) * 8;
  const ushort* ga0 = &A[(long)(m0 + w * 32 + (lane >> 2)) * lda + kk];
  const ushort* ga1 = ga0 + (long)16 * lda;
  const ushort* gb = &B[(long)(n0 + w * 16 + (lane >> 2)) * ldb + kk];

  auto stage = [&](int bi) {
    gload16(ga0, &As[bi][w * 1024]);
    gload16(ga1, &As[bi][w * 1024 + 512]);
    gload16(gb, &Bs[bi][w * 512]);
    ga0 += 32; ga1 += 32; gb += 32;
  };
  auto compute = [&](int bi) {
    short8 a[4], bfr[2];
#pragma unroll
    for (int i = 0; i < 4; ++i)
      a[i] = *(const short8*)&As[bi][(wr + 16 * i + fm) * 32 + q4 * 8];
#pragma unroll
    for (int j = 0; j < 2; ++j)
      bfr[j] = *(const short8*)&Bs[bi][(wc + 16 * j + fm) * 32 + q4 * 8];
#pragma unroll
    for (int i = 0; i < 4; ++i)
#pragma unroll
      for (int j = 0; j < 2; ++j)
        acc[i][j] = __builtin_amdgcn_mfma_f32_16x16x32_bf16(a[i], bfr[j], acc[i][j], 0, 0, 0);
  };

  // prologue: stage K-step 0 into buf0
  stage(0);
  __syncthreads();  // drains vmcnt(0): buf0 ready
#pragma unroll 1
  for (int k0 = 0; k0 < K; k0 += 64) {
    stage(1);        // prefetch k0+32 (K multiple of 64 -> always valid)
    compute(0);
    __syncthreads();  // buf1 ready; buf0 reads done
    if (k0 + 64 < K) stage(0);  // prefetch k0+64
    compute(1);
    __syncthreads();
  }

#pragma unroll
  for (int j = 0; j < 2; ++j) {
    int col = n0 + wc + 16 * j + fm;
    float bv = bias ? bias[col] : 0.f;
#pragma unroll
    for (int i = 0; i < 4; ++i) {
      int row0 = m0 + wr + 16 * i + q4 * 4;
      float vv[4];
#pragma unroll
      for (int r = 0; r < 4; ++r) {
        float v = acc[i][j][r] + bv;
        if (GELU_) v = 0.5f * v * (1.f + erff(v * 0.7071067811865476f));
        vv[r] = v;
        if (CBF16)
          ((ushort*)Cv)[(long)(row0 + r) * ldc + col] = f2bf(v);
        else
          ((float*)Cv)[(long)(row0 + r) * ldc + col] = v;
      }
      if (VST && n0 >= 1024) {  // V region: also store transposed [bh][d][s]
        int d = (col - 1024) & 63;
        int hh = (n0 - 1024) >> 6;
        int bb = row0 >> 9, s0 = row0 & 511;
        ushort4v pk;
#pragma unroll
        for (int r = 0; r < 4; ++r) pk[r] = f2bf(vv[r]);
        *(ushort4v*)&vTout[((long)(bb * 8 + hh) * 64 + d) * 512 + s0] = pk;
      }
    }
  }
}

// ---------------- fused attention ----------------
// grid (16 mtiles, 64 bh), 256 threads (4 waves). 32 rows per block.
// Q/K frags direct from qkv (L2), V frags direct from vT (L2); Ps in LDS.
// series/prior/sigma stores are NON-TEMPORAL (nt) -> don't thrash L2.
__global__ __launch_bounds__(256, 2) void attn_fused(
    const ushort* __restrict__ qkv, const ushort* __restrict__ vT,
    const float* __restrict__ h, const float* __restrict__ WsT,
    const float* __restrict__ bsw,
    float* __restrict__ series, float* __restrict__ prior,
    float* __restrict__ sigma, ushort* __restrict__ t1b) {
  __shared__ ushort Ps[32 * 520];  // softmax'd P, bf16 (33.3 KB)
  __shared__ float red[128];
  __shared__ float sgc[96];

  int t = threadIdx.x;
  int m0 = blockIdx.x * 32;
  int bh = blockIdx.y;
  int b = bh >> 3, hh = bh & 7;
  int w = t >> 6, lane = t & 63;
  int fm = lane & 15, q4 = lane >> 4;
  int wc = w * 128;
  long rowg = (long)b * 512;

  // ---- fused sigma logits: 8 threads per row, 64 k each ----
  {
    int r = t >> 3, p = t & 7;
    const float* hrow = &h[(rowg + m0 + r) * 512 + p * 64];
    const float* wcol = &WsT[hh * 512 + p * 64];
    float s = 0.f;
#pragma unroll
    for (int i = 0; i < 16; ++i) {
      float4 hv = *(const float4*)&hrow[i * 4];
      float4 wv = *(const float4*)&wcol[i * 4];
      s += hv.x * wv.x + hv.y * wv.y + hv.z * wv.z + hv.w * wv.w;
    }
    s += __shfl_xor(s, 1); s += __shfl_xor(s, 2); s += __shfl_xor(s, 4);
    if (p == 0) {
      float xv = s + bsw[hh];
      float sig = 1.f / (1.f + __expf(-5.f * xv)) + 1e-5f;
      float sgv = expm1f(sig * 1.0986122886681098f);
      sgc[r * 3] = sgv;
      sgc[r * 3 + 1] = 0.3989422804014327f / sgv;
      sgc[r * 3 + 2] = 1.f / sgv;
    }
  }

  // ---- S = Q @ K^T, fragments straight from global (L2-resident) ----
  float4v acc[2][8];
#pragma unroll
  for (int i = 0; i < 2; ++i)
#pragma unroll
    for (int j = 0; j < 8; ++j) acc[i][j] = (float4v){0.f, 0.f, 0.f, 0.f};

  const ushort* qbase = &qkv[(rowg + m0) * 1536 + hh * 64];
  const ushort* kbase = &qkv[rowg * 1536 + 512 + hh * 64];
#pragma unroll
  for (int ks = 0; ks < 2; ++ks) {
    int ko = ks * 32 + q4 * 8;
    short8 a[2], bfr[8];
#pragma unroll
    for (int i = 0; i < 2; ++i)
      a[i] = *(const short8*)&qbase[(long)(16 * i + fm) * 1536 + ko];
#pragma unroll
    for (int j = 0; j < 8; ++j)
      bfr[j] = *(const short8*)&kbase[(long)(wc + 16 * j + fm) * 1536 + ko];
#pragma unroll
    for (int i = 0; i < 2; ++i)
#pragma unroll
      for (int j = 0; j < 8; ++j)
        acc[i][j] = __builtin_amdgcn_mfma_f32_16x16x32_bf16(a[i], bfr[j], acc[i][j], 0, 0, 0);
  }

  // ---- softmax over full rows (512 cols per row) ----
#pragma unroll
  for (int i = 0; i < 2; ++i)
#pragma unroll
    for (int j = 0; j < 8; ++j)
#pragma unroll
      for (int r = 0; r < 4; ++r) acc[i][j][r] *= 0.125f;

  float mrow[2][4];
#pragma unroll
  for (int i = 0; i < 2; ++i)
#pragma unroll
    for (int r = 0; r < 4; ++r) {
      float m = acc[i][0][r];
#pragma unroll
      for (int j = 1; j < 8; ++j) m = fmaxf(m, acc[i][j][r]);
#pragma unroll
      for (int off = 1; off < 16; off <<= 1) m = fmaxf(m, __shfl_xor(m, off));
      mrow[i][r] = m;
    }
  if (fm == 0) {
#pragma unroll
    for (int i = 0; i < 2; ++i)
#pragma unroll
      for (int r = 0; r < 4; ++r)
        red[(16 * i + q4 * 4 + r) * 4 + w] = mrow[i][r];
  }
  __syncthreads();
#pragma unroll
  for (int i = 0; i < 2; ++i)
#pragma unroll
    for (int r = 0; r < 4; ++r) {
      const float* rp = &red[(16 * i + q4 * 4 + r) * 4];
      mrow[i][r] = fmaxf(fmaxf(rp[0], rp[1]), fmaxf(rp[2], rp[3]));
    }
  float lrow[2][4];
#pragma unroll
  for (int i = 0; i < 2; ++i)
#pragma unroll
    for (int r = 0; r < 4; ++r) {
      float s = 0.f;
#pragma unroll
      for (int j = 0; j < 8; ++j) {
        float e = __expf(acc[i][j][r] - mrow[i][r]);
        acc[i][j][r] = e;
        s += e;
      }
#pragma unroll
      for (int off = 1; off < 16; off <<= 1) s += __shfl_xor(s, off);
      lrow[i][r] = s;
    }
  __syncthreads();  // all waves done reading red(max)
  if (fm == 0) {
#pragma unroll
    for (int i = 0; i < 2; ++i)
#pragma unroll
      for (int r = 0; r < 4; ++r)
        red[(16 * i + q4 * 4 + r) * 4 + w] = lrow[i][r];
  }
  __syncthreads();
#pragma unroll
  for (int i = 0; i < 2; ++i)
#pragma unroll
    for (int r = 0; r < 4; ++r) {
      const float* rp = &red[(16 * i + q4 * 4 + r) * 4];
      lrow[i][r] = 1.f / (rp[0] + rp[1] + rp[2] + rp[3]);
    }

  // ---- write series (fp32 global, nt) + Ps (bf16 LDS) ----
  float* serp = series + ((long)bh << 18);
#pragma unroll
  for (int i = 0; i < 2; ++i)
#pragma unroll
    for (int r = 0; r < 4; ++r) {
      int row = 16 * i + q4 * 4 + r;
      float inv = lrow[i][r];
#pragma unroll
      for (int j = 0; j < 8; ++j) {
        int col = wc + 16 * j + fm;
        float v = acc[i][j][r] * inv;
        __builtin_nontemporal_store(v, &serp[(long)(m0 + row) * 512 + col]);
        Ps[row * 520 + col] = f2bf(v);
      }
    }
  __syncthreads();  // Ps (and sgc) visible to all waves

  // ---- O = P @ V : V frags direct from vT (L2), zero barriers ----
  float4v acc2[2] = {{0.f, 0.f, 0.f, 0.f}, {0.f, 0.f, 0.f, 0.f}};
  int wn = w * 16;
  const ushort* vbase = &vT[((long)bh * 64 + wn + fm) * 512];
#pragma unroll
  for (int c = 0; c < 8; ++c) {
#pragma unroll
    for (int ks = 0; ks < 2; ++ks) {
      int ko = ks * 32 + q4 * 8;
      short8 b2 = *(const short8*)&vbase[c * 64 + ko];
#pragma unroll
      for (int i = 0; i < 2; ++i) {
        short8 a2 = *(const short8*)&Ps[(16 * i + fm) * 520 + c * 64 + ko];
        acc2[i] = __builtin_amdgcn_mfma_f32_16x16x32_bf16(a2, b2, acc2[i], 0, 0, 0);
      }
    }
  }
#pragma unroll
  for (int i = 0; i < 2; ++i)
#pragma unroll
    for (int r = 0; r < 4; ++r)
      t1b[(rowg + m0 + 16 * i + q4 * 4 + r) * 512 + hh * 64 + wn + fm] =
          f2bf(acc2[i][r]);

  // ---- prior + sigma for rows m0..m0+31 (nt stores, ext_vector type) ----
  float* prip = prior + ((long)bh << 18);
  float* sigp = sigma + ((long)bh << 18);
  for (int it = t; it < 4096; it += 256) {
    int row = it >> 7;
    int c4 = (it & 127) << 2;
    float sgv = sgc[row * 3], inv = sgc[row * 3 + 1], rinv = sgc[row * 3 + 2];
    float ig = (float)(m0 + row);
    float4v pv, sv;
#pragma unroll
    for (int e = 0; e < 4; ++e) {
      float dd = ig - (float)(c4 + e);
      float rr = dd * rinv;
      pv[e] = inv * __expf(-0.5f * rr * rr);
      sv[e] = sgv;
    }
    __builtin_nontemporal_store(pv, (float4v*)&prip[(long)(m0 + row) * 512 + c4]);
    __builtin_nontemporal_store(sv, (float4v*)&sigp[(long)(m0 + row) * 512 + c4]);
  }
}

// ---------------- residual + layernorm (fp32 out + optional bf16 out) -------
__global__ __launch_bounds__(256) void ln_kernel(const float* __restrict__ x,
                                                 const float* __restrict__ delta,
                                                 const float* __restrict__ g,
                                                 const float* __restrict__ bb,
                                                 float* __restrict__ out,
                                                 ushort* __restrict__ hb) {
  long row = blockIdx.x;
  int tid = threadIdx.x;
  int c = tid * 2;
  float2 xv = *(const float2*)&x[row * 512 + c];
  if (delta) {
    float2 dv = *(const float2*)&delta[row * 512 + c];
    xv.x += dv.x; xv.y += dv.y;
  }
  float s = xv.x + xv.y;
  float q = xv.x * xv.x + xv.y * xv.y;
#pragma unroll
  for (int off = 1; off < 64; off <<= 1) {
    s += __shfl_xor(s, off);
    q += __shfl_xor(q, off);
  }
  __shared__ float red[8];
  int wid = tid >> 6;
  if ((tid & 63) == 0) { red[wid] = s; red[wid + 4] = q; }
  __syncthreads();
  float S = red[0] + red[1] + red[2] + red[3];
  float Q = red[4] + red[5] + red[6] + red[7];
  float mean = S * (1.f / 512.f);
  float var = Q * (1.f / 512.f) - mean * mean;
  float rstd = rsqrtf(var + 1e-3f);
  float2 o;
  o.x = (xv.x - mean) * rstd * g[c] + bb[c];
  o.y = (xv.y - mean) * rstd * g[c + 1] + bb[c + 1];
  *(float2*)&out[row * 512 + c] = o;
  if (hb) {
    unsigned pk = ((unsigned)f2bf(o.y) << 16) | (unsigned)f2bf(o.x);
    ((unsigned*)hb)[row * 256 + tid] = pk;
  }
}

// ---------------- final LN + projection (wave per row) ----------------
__global__ __launch_bounds__(256) void proj_ln(const float* __restrict__ A,
                                               const float* __restrict__ g,
                                               const float* __restrict__ bb,
                                               const float* __restrict__ W,
                                               const float* __restrict__ bp,
                                               float* __restrict__ C) {
  long row = (long)blockIdx.x * 4 + (threadIdx.x >> 6);
  int lane = threadIdx.x & 63;
  int k0 = lane * 8;
  float xv[8];
  {
    float4 x0 = *(const float4*)&A[row * 512 + k0];
    float4 x1 = *(const float4*)&A[row * 512 + k0 + 4];
    xv[0] = x0.x; xv[1] = x0.y; xv[2] = x0.z; xv[3] = x0.w;
    xv[4] = x1.x; xv[5] = x1.y; xv[6] = x1.z; xv[7] = x1.w;
  }
  float s = 0.f, q = 0.f;
#pragma unroll
  for (int e = 0; e < 8; ++e) { s += xv[e]; q += xv[e] * xv[e]; }
#pragma unroll
  for (int off = 1; off < 64; off <<= 1) {
    s += __shfl_xor(s, off);
    q += __shfl_xor(q, off);
  }
  float mean = s * (1.f / 512.f);
  float var = q * (1.f / 512.f) - mean * mean;
  float rstd = rsqrtf(var + 1e-3f);
  float acc[38];
#pragma unroll
  for (int j = 0; j < 38; ++j) acc[j] = 0.f;
#pragma unroll
  for (int e = 0; e < 8; ++e) {
    float xn = (xv[e] - mean) * rstd * g[k0 + e] + bb[k0 + e];
    const float* wr = &W[(long)(k0 + e) * 38];
#pragma unroll
    for (int j = 0; j < 38; ++j) acc[j] = fmaf(xn, wr[j], acc[j]);
  }
#pragma unroll
  for (int j = 0; j < 38; ++j)
#pragma unroll
    for (int off = 32; off; off >>= 1) acc[j] += __shfl_xor(acc[j], off);
  if (lane == 0) {
#pragma unroll
    for (int j = 0; j < 38; ++j) C[row * 38 + j] = acc[j] + bp[j];
  }
}

extern "C" void kernel_launch(void* const* d_in, const int* in_sizes, int n_in,
                              void* d_out, int out_size, void* d_ws, size_t ws_size,
                              hipStream_t stream) {
  (void)in_sizes; (void)n_in; (void)out_size; (void)ws_size;
  const float* x    = (const float*)d_in[0];
  const float* ck   = (const float*)d_in[1];
  const float* Wq   = (const float*)d_in[2];
  const float* bq   = (const float*)d_in[3];
  const float* Wk   = (const float*)d_in[4];
  const float* bk   = (const float*)d_in[5];
  const float* Wv   = (const float*)d_in[6];
  const float* bv   = (const float*)d_in[7];
  const float* Wsw  = (const float*)d_in[8];
  const float* bsw  = (const float*)d_in[9];
  const float* Wo   = (const float*)d_in[10];
  const float* bo   = (const float*)d_in[11];
  const float* W1   = (const float*)d_in[12];
  const float* b1   = (const float*)d_in[13];
  const float* W2   = (const float*)d_in[14];
  const float* b2   = (const float*)d_in[15];
  const float* ln1g = (const float*)d_in[16];
  const float* ln1b = (const float*)d_in[17];
  const float* ln2g = (const float*)d_in[18];
  const float* ln2b = (const float*)d_in[19];
  const float* lnfg = (const float*)d_in[20];
  const float* lnfb = (const float*)d_in[21];
  const float* Wp   = (const float*)d_in[22];
  const float* bp   = (const float*)d_in[23];
  float* out = (float*)d_out;

  // ws layout (same footprint)
  float* h    = (float*)d_ws;
  float* t1   = h + 2097152;
  float* t2   = t1 + 2097152;
  float* wst  = t2 + 2097152;           // 12288 used of 32768 slot
  float* bqkv = wst + 32768;            // 4608
  ushort* qkv  = (ushort*)(bqkv + 4608);        // 4096*1536
  ushort* wqkv = qkv + 6291456;                 // 3*1536*512
  ushort* wo3  = wqkv + 2359296;                // 3*512*512
  ushort* w13  = wo3 + 786432;
  ushort* w23  = w13 + 786432;
  // overlays: t1b = low half of t1 (bf16); hb = high half of t1;
  // vT = low half of t2 (dead before Wo writes t2).
  ushort* t1b = (ushort*)t1;                    // 2097152 ushorts
  ushort* hb  = (ushort*)(t1 + 1048576);        // 2097152 ushorts
  ushort* vT  = (ushort*)t2;                    // 2097152 ushorts

  float* series0 = out + 155648;
  float* prior0  = out + 50487296;
  float* sigma0  = out + 100818944;

  dim3 gPrep(2, 64, 18);
  prep_kernel<<<gPrep, 256, 0, stream>>>(Wq, Wk, Wv, Wo, W1, W2,
                                         wqkv, wo3, w13, w23);
  bw_kernel<<<6, 512, 0, stream>>>(bq, bk, bv, Wsw, bqkv, wst);

  embed_kernel<<<4096, 512, 0, stream>>>(x, ck, h, hb);

  dim3 gQKV(24, 32, 1);   // N=1536, M=4096 (BN=64, BM=128)
  dim3 gFull(8, 32, 1);   // N=512,  M=4096
  dim3 gAttn(16, 64, 1);  // 16 mtiles x 64 bh

  for (int l = 0; l < 3; ++l) {
    float* ser = series0 + (long)l * 16777216;
    float* pri = prior0  + (long)l * 16777216;
    float* sgm = sigma0  + (long)l * 16777216;

    // fused QKV projection -> qkv bf16 [4096][1536] + vT co-store
    gemm_bt<false, true, true><<<gQKV, 256, 0, stream>>>(
        hb, 512, wqkv + (long)l * 786432, 512, bqkv + l * 1536, qkv, 1536, 512, vT);
    // fused attention: series/prior/sigma + sigma-logits + attn-out (t1b)
    attn_fused<<<gAttn, 256, 0, stream>>>(qkv, vT, h, wst + (long)l * 4096,
                                          bsw + (long)l * 8, ser, pri, sgm, t1b);
    // Wo projection (f32 out for residual)
    gemm_bt<false, false, false><<<gFull, 256, 0, stream>>>(
        t1b, 512, wo3 + (long)l * 262144, 512, bo + (long)l * 512, t2, 512, 512, nullptr);
    ln_kernel<<<4096, 256, 0, stream>>>(h, t2, ln1g + l * 512, ln1b + l * 512, h, hb);
    // FF
    gemm_bt<true, true, false><<<gFull, 256, 0, stream>>>(
        hb, 512, w13 + (long)l * 262144, 512, b1 + (long)l * 512, t1b, 512, 512, nullptr);
    gemm_bt<false, false, false><<<gFull, 256, 0, stream>>>(
        t1b, 512, w23 + (long)l * 262144, 512, b2 + (long)l * 512, t2, 512, 512, nullptr);
    ln_kernel<<<4096, 256, 0, stream>>>(h, t2, ln2g + l * 512, ln2b + l * 512, h, hb);
  }

  proj_ln<<<1024, 256, 0, stream>>>(h, lnfg, lnfb, Wp, bp, out);
}